// Round 2
// baseline (321.551 us; speedup 1.0000x reference)
//
#include <hip/hip_runtime.h>

#define NC 19
#define NPK 20               // packed u16-pair registers: 10 for U, 10 for I
#define EPS 1e-5f

// Per-element update: u[c] += (t==c)+(p==c); inter[c] += (q==c) with q = (t==p)? t : sentinel.
__device__ __forceinline__ void count_one(int t, int p,
                                          unsigned* __restrict__ u,
                                          unsigned* __restrict__ itc)
{
    int q = (t == p) ? t : NC;   // NC never matches a class
    #pragma unroll
    for (int c = 0; c < NC; ++c) {
        u[c]   += (unsigned)(t == c);
        u[c]   += (unsigned)(p == c);
        itc[c] += (unsigned)(q == c);
    }
}

__global__ __launch_bounds__(256) void dice_main(
    const int4* __restrict__ yp, const int4* __restrict__ yt,
    unsigned* __restrict__ gU, unsigned* __restrict__ gI,
    unsigned* __restrict__ ticket, float* __restrict__ out, int n4)
{
    unsigned u[NC], itc[NC];
    #pragma unroll
    for (int c = 0; c < NC; ++c) { u[c] = 0u; itc[c] = 0u; }

    // Main loop: pure VALU counting, no LDS atomics.
    const int stride = gridDim.x * 256;
    for (int i = blockIdx.x * 256 + threadIdx.x; i < n4; i += stride) {
        int4 p4 = yp[i];
        int4 t4 = yt[i];
        count_one(t4.x, p4.x, u, itc);
        count_one(t4.y, p4.y, u, itc);
        count_one(t4.z, p4.z, u, itc);
        count_one(t4.w, p4.w, u, itc);
    }

    // Pack class pairs into u16 halves (per-thread counts <= 128, per-wave sums <= 8192).
    unsigned P[NPK];
    #pragma unroll
    for (int j = 0; j < 10; ++j) {
        unsigned bu = (2*j + 1 < NC) ? u[2*j + 1]   : 0u;
        unsigned bi = (2*j + 1 < NC) ? itc[2*j + 1] : 0u;
        P[j]      = u[2*j]   | (bu << 16);
        P[10 + j] = itc[2*j] | (bi << 16);
    }

    // 64-lane butterfly reduce on 20 packed values.
    #pragma unroll
    for (int j = 0; j < NPK; ++j) {
        #pragma unroll
        for (int off = 1; off < 64; off <<= 1)
            P[j] += __shfl_xor(P[j], off, 64);
    }

    __shared__ unsigned ldsP[4 * NPK];
    __shared__ unsigned s_old;
    const int lane = threadIdx.x & 63;
    const int wv   = threadIdx.x >> 6;
    if (lane == 0) {
        #pragma unroll
        for (int j = 0; j < NPK; ++j) ldsP[wv * NPK + j] = P[j];
    }
    __syncthreads();

    // Threads 0..19: merge 4 waves (unpack first — u32 math), then global atomics.
    if (threadIdx.x < NPK) {
        unsigned lo = 0, hi = 0;
        #pragma unroll
        for (int w = 0; w < 4; ++w) {
            unsigned v = ldsP[w * NPK + threadIdx.x];
            lo += v & 0xffffu;
            hi += v >> 16;
        }
        const int j = threadIdx.x;
        unsigned* base = (j < 10) ? gU : gI;
        const int c0 = (j < 10) ? 2*j : 2*(j - 10);
        atomicAdd(&base[c0], lo);
        if (c0 + 1 < NC) atomicAdd(&base[c0 + 1], hi);
    }

    // Last block computes the dice loss (fused finalization).
    __threadfence();
    __syncthreads();
    if (threadIdx.x == 0)
        s_old = __hip_atomic_fetch_add(ticket, 1u, __ATOMIC_ACQ_REL, __HIP_MEMORY_SCOPE_AGENT);
    __syncthreads();
    if (s_old == gridDim.x - 1 && threadIdx.x < 64) {
        float dice = 0.0f;
        if (lane < NC) {
            unsigned Uv = __hip_atomic_load(&gU[lane], __ATOMIC_RELAXED, __HIP_MEMORY_SCOPE_AGENT);
            unsigned Iv = __hip_atomic_load(&gI[lane], __ATOMIC_RELAXED, __HIP_MEMORY_SCOPE_AGENT);
            float I = (float)Iv;
            float U = (float)Uv;          // U = count_y + count_p; union = U - I
            dice = (2.0f * I + EPS) / ((U - I) + EPS);
        }
        #pragma unroll
        for (int off = 32; off > 0; off >>= 1)
            dice += __shfl_down(dice, off, 64);
        if (lane == 0) out[0] = 1.0f - dice * (1.0f / (float)NC);
    }
}

extern "C" void kernel_launch(void* const* d_in, const int* in_sizes, int n_in,
                              void* d_out, int out_size, void* d_ws, size_t ws_size,
                              hipStream_t stream)
{
    const int4* yp = (const int4*)d_in[0];   // y_pred, int32
    const int4* yt = (const int4*)d_in[1];   // y,      int32
    unsigned* gU     = (unsigned*)d_ws;      // 19 u32: count_y + count_p
    unsigned* gI     = gU + NC;              // 19 u32: intersection
    unsigned* ticket = gI + NC;              // 1 u32
    float* out = (float*)d_out;

    const int n  = in_sizes[0];              // 16*1024*1024
    const int n4 = n >> 2;

    hipMemsetAsync(d_ws, 0, (2 * NC + 1) * sizeof(unsigned), stream);

    // grid 1024: 4 blocks/CU (16 waves/CU), 16 int4 per thread; per-thread
    // class counts <= 128 so u16 packing in the epilogue cannot overflow.
    dice_main<<<1024, 256, 0, stream>>>(yp, yt, gU, gI, ticket, out, n4);
}

// Round 3
// 280.446 us; speedup vs baseline: 1.1466x; 1.1466x over previous
//
#include <hip/hip_runtime.h>

#define NC 19
#define NPK 20               // packed u16-pair registers: 10 for U, 10 for I
#define EPS 1e-5f

typedef unsigned long long u64;

// Add 1 to 6-bit field for class value encoded as s6 = 6*cls.
// Classes 0..9 live in lo (shifts 0..54), classes 10..19 in hi (shifts 0..54
// after -60). The not-selected half adds (0 << garbage) == 0, so no branch.
__device__ __forceinline__ void acc6(u64& lo, u64& hi, unsigned s6) {
    unsigned islo = (s6 < 60u) ? 1u : 0u;
    lo += (u64)islo << (s6 & 63u);
    hi += (u64)(islo ^ 1u) << ((s6 - 60u) & 63u);
}

__device__ __forceinline__ void elem(int t, int p,
                                     u64& tlo, u64& thi,
                                     u64& plo, u64& phi,
                                     u64& qlo, u64& qhi) {
    unsigned t6 = (unsigned)t * 6u;
    unsigned p6 = (unsigned)p * 6u;
    unsigned q6 = (t == p) ? t6 : 114u;   // sentinel class 19 -> junk field
    acc6(tlo, thi, t6);
    acc6(plo, phi, p6);
    acc6(qlo, qhi, q6);
}

__global__ __launch_bounds__(256) void dice_main(
    const int4* __restrict__ yp, const int4* __restrict__ yt,
    unsigned* __restrict__ gU, unsigned* __restrict__ gI,
    unsigned* __restrict__ ticket, float* __restrict__ out, int n4)
{
    unsigned cntU[NC], cntI[NC];
    #pragma unroll
    for (int c = 0; c < NC; ++c) { cntU[c] = 0u; cntI[c] = 0u; }

    const int stride = gridDim.x * 256;
    int i = blockIdx.x * 256 + threadIdx.x;

    // Outer: phases of 8 int4-iterations (max 32 adds/field <= 63, no overflow),
    // then unpack the 6-bit fields into u32 counters.
    while (i < n4) {
        u64 tlo = 0, thi = 0, plo = 0, phi = 0, qlo = 0, qhi = 0;
        #pragma unroll
        for (int k = 0; k < 8; ++k) {
            int idx = i + k * stride;
            if (idx < n4) {
                int4 tv = yt[idx];
                int4 pv = yp[idx];
                elem(tv.x, pv.x, tlo, thi, plo, phi, qlo, qhi);
                elem(tv.y, pv.y, tlo, thi, plo, phi, qlo, qhi);
                elem(tv.z, pv.z, tlo, thi, plo, phi, qlo, qhi);
                elem(tv.w, pv.w, tlo, thi, plo, phi, qlo, qhi);
            }
        }
        i += 8 * stride;

        #pragma unroll
        for (int k = 0; k < 10; ++k) {
            cntU[k] += ((unsigned)(tlo >> (6 * k)) & 63u)
                     + ((unsigned)(plo >> (6 * k)) & 63u);
            cntI[k] += ((unsigned)(qlo >> (6 * k)) & 63u);
        }
        #pragma unroll
        for (int k = 0; k < 9; ++k) {
            cntU[10 + k] += ((unsigned)(thi >> (6 * k)) & 63u)
                          + ((unsigned)(phi >> (6 * k)) & 63u);
            cntI[10 + k] += ((unsigned)(qhi >> (6 * k)) & 63u);
        }
    }

    // ---- epilogue (verified in R2): pack u16 pairs, butterfly, LDS, atomics ----
    unsigned P[NPK];
    #pragma unroll
    for (int j = 0; j < 10; ++j) {
        unsigned bu = (2 * j + 1 < NC) ? cntU[2 * j + 1] : 0u;
        unsigned bi = (2 * j + 1 < NC) ? cntI[2 * j + 1] : 0u;
        P[j]      = cntU[2 * j] | (bu << 16);
        P[10 + j] = cntI[2 * j] | (bi << 16);
    }

    #pragma unroll
    for (int j = 0; j < NPK; ++j) {
        #pragma unroll
        for (int off = 1; off < 64; off <<= 1)
            P[j] += __shfl_xor(P[j], off, 64);
    }

    __shared__ unsigned ldsP[4 * NPK];
    __shared__ unsigned s_old;
    const int lane = threadIdx.x & 63;
    const int wv   = threadIdx.x >> 6;
    if (lane == 0) {
        #pragma unroll
        for (int j = 0; j < NPK; ++j) ldsP[wv * NPK + j] = P[j];
    }
    __syncthreads();

    if (threadIdx.x < NPK) {
        unsigned lo = 0, hi = 0;
        #pragma unroll
        for (int w = 0; w < 4; ++w) {
            unsigned v = ldsP[w * NPK + threadIdx.x];
            lo += v & 0xffffu;
            hi += v >> 16;
        }
        const int j = threadIdx.x;
        unsigned* base = (j < 10) ? gU : gI;
        const int c0 = (j < 10) ? 2 * j : 2 * (j - 10);
        atomicAdd(&base[c0], lo);
        if (c0 + 1 < NC) atomicAdd(&base[c0 + 1], hi);
    }

    // Last block computes the dice loss (fused finalization).
    __threadfence();
    __syncthreads();
    if (threadIdx.x == 0)
        s_old = __hip_atomic_fetch_add(ticket, 1u, __ATOMIC_ACQ_REL, __HIP_MEMORY_SCOPE_AGENT);
    __syncthreads();
    if (s_old == gridDim.x - 1 && threadIdx.x < 64) {
        float dice = 0.0f;
        if (lane < NC) {
            unsigned Uv = __hip_atomic_load(&gU[lane], __ATOMIC_RELAXED, __HIP_MEMORY_SCOPE_AGENT);
            unsigned Iv = __hip_atomic_load(&gI[lane], __ATOMIC_RELAXED, __HIP_MEMORY_SCOPE_AGENT);
            float I = (float)Iv;
            float U = (float)Uv;          // U = count_y + count_p; union = U - I
            dice = (2.0f * I + EPS) / ((U - I) + EPS);
        }
        #pragma unroll
        for (int off = 32; off > 0; off >>= 1)
            dice += __shfl_down(dice, off, 64);
        if (lane == 0) out[0] = 1.0f - dice * (1.0f / (float)NC);
    }
}

extern "C" void kernel_launch(void* const* d_in, const int* in_sizes, int n_in,
                              void* d_out, int out_size, void* d_ws, size_t ws_size,
                              hipStream_t stream)
{
    const int4* yp = (const int4*)d_in[0];   // y_pred, int32
    const int4* yt = (const int4*)d_in[1];   // y,      int32
    unsigned* gU     = (unsigned*)d_ws;      // 19 u32: count_y + count_p
    unsigned* gI     = gU + NC;              // 19 u32: intersection
    unsigned* ticket = gI + NC;              // 1 u32
    float* out = (float*)d_out;

    const int n  = in_sizes[0];              // 16*1024*1024
    const int n4 = n >> 2;

    hipMemsetAsync(d_ws, 0, (2 * NC + 1) * sizeof(unsigned), stream);

    // grid 1024: 4 blocks/CU, 16 int4-iterations per thread (2 phases of 8).
    dice_main<<<1024, 256, 0, stream>>>(yp, yt, gU, gI, ticket, out, n4);
}